// Round 4
// baseline (1457.572 us; speedup 1.0000x reference)
//
#include <hip/hip_runtime.h>
#include <cstdint>
#include <cstddef>

typedef _Float16 half8 __attribute__((ext_vector_type(8)));
typedef _Float16 half4_t __attribute__((ext_vector_type(4)));
typedef _Float16 half2_t __attribute__((ext_vector_type(2)));
typedef float f32x4 __attribute__((ext_vector_type(4)));
typedef unsigned int uint4_t __attribute__((ext_vector_type(4)));

#define LOG2E 1.4426950408889634f

// async global->LDS, 16B per lane. LDS dest must be wave-uniform base + lane*16.
__device__ __forceinline__ void async16(const void* g, void* l) {
  __builtin_amdgcn_global_load_lds((const __attribute__((address_space(1))) void*)g,
                                   (__attribute__((address_space(3))) void*)l,
                                   16, 0, 0);
}

__device__ __forceinline__ f32x4 vmax4(f32x4 a, f32x4 b) {
  f32x4 r;
  r[0] = fmaxf(a[0], b[0]); r[1] = fmaxf(a[1], b[1]);
  r[2] = fmaxf(a[2], b[2]); r[3] = fmaxf(a[3], b[3]);
  return r;
}

// fmaxf(fmaxf(a,b),c) fuses to v_max3_f32
__device__ __forceinline__ f32x4 vmax4_3(f32x4 a, f32x4 b, f32x4 c) {
  f32x4 r;
  r[0] = fmaxf(fmaxf(a[0], b[0]), c[0]);
  r[1] = fmaxf(fmaxf(a[1], b[1]), c[1]);
  r[2] = fmaxf(fmaxf(a[2], b[2]), c[2]);
  r[3] = fmaxf(fmaxf(a[3], b[3]), c[3]);
  return r;
}

__device__ __forceinline__ half2_t pk_cvt(float a, float b) {
  return __builtin_bit_cast(half2_t, __builtin_amdgcn_cvt_pkrtz(a, b));
}

// raw v_exp_f32 (skips OCML denormal fixup; args are <= 0, outputs in [0,1])
__device__ __forceinline__ float fexp2(float x) { return __builtin_amdgcn_exp2f(x); }

// gfx950 cross-lane swaps (both operands read+write, pure register ops):
// permlane32_swap: vdst.hi32lanes <-> vsrc.lo32lanes
// permlane16_swap: vdst.row1 <-> vsrc.row0, vdst.row3 <-> vsrc.row2 (16-lane rows)
__device__ __forceinline__ void plswap32(unsigned& a, unsigned& b) {
  asm("v_permlane32_swap_b32 %0, %1" : "+v"(a), "+v"(b));
}
__device__ __forceinline__ void plswap16(unsigned& a, unsigned& b) {
  asm("v_permlane16_swap_b32 %0, %1" : "+v"(a), "+v"(b));
}

// ---------------- fp32 -> fp16 convert ----------------
__global__ __launch_bounds__(256) void cvt_f32_f16(const float* __restrict__ in,
                                                   _Float16* __restrict__ out, int n) {
  int i = (blockIdx.x * 256 + threadIdx.x) * 8;
  if (i + 7 < n) {
    f32x4 a = *(const f32x4*)(in + i);
    f32x4 b = *(const f32x4*)(in + i + 4);
    half8 h;
    h[0] = (_Float16)a[0]; h[1] = (_Float16)a[1];
    h[2] = (_Float16)a[2]; h[3] = (_Float16)a[3];
    h[4] = (_Float16)b[0]; h[5] = (_Float16)b[1];
    h[6] = (_Float16)b[2]; h[7] = (_Float16)b[3];
    *(half8*)(out + i) = h;
  }
}

// 4 weight matrices (1M elems each) in one launch
__global__ __launch_bounds__(256) void cvt_w4(
    const float* __restrict__ a, const float* __restrict__ b,
    const float* __restrict__ c, const float* __restrict__ d,
    _Float16* __restrict__ oa, _Float16* __restrict__ ob,
    _Float16* __restrict__ oc, _Float16* __restrict__ od) {
  int seg = blockIdx.x >> 9;
  const float* src = (seg == 0) ? a : (seg == 1) ? b : (seg == 2) ? c : d;
  _Float16* dst = (seg == 0) ? oa : (seg == 1) ? ob : (seg == 2) ? oc : od;
  int i = ((blockIdx.x & 511) * 256 + threadIdx.x) * 8;
  f32x4 x0 = *(const f32x4*)(src + i);
  f32x4 x1 = *(const f32x4*)(src + i + 4);
  half8 h;
  h[0] = (_Float16)x0[0]; h[1] = (_Float16)x0[1];
  h[2] = (_Float16)x0[2]; h[3] = (_Float16)x0[3];
  h[4] = (_Float16)x1[0]; h[5] = (_Float16)x1[1];
  h[6] = (_Float16)x1[2]; h[7] = (_Float16)x1[3];
  *(half8*)(dst + i) = h;
}

// ---------------- shared 128x128x1024 NT-GEMM mainloop ----------------
// Double-buffered LDS, issue-early / sync-late (T3-minimum pipeline).
__device__ __forceinline__ void gemm128_mainloop(const _Float16* __restrict__ Ap,
                                                 const _Float16* __restrict__ Wp,
                                                 _Float16* As, _Float16* Bs,
                                                 f32x4 (&acc)[4][4]) {
  const int tid = threadIdx.x;
  const int lane = tid & 63;
  const int wid = tid >> 6;
  const int c = lane & 15, quad = lane >> 4;
  const int wm0 = (wid >> 1) * 64, wn0 = (wid & 1) * 64;
  const _Float16* ga0 = Ap + (size_t)(tid >> 2) * 1024 + (tid & 3) * 8;
  const _Float16* ga1 = ga0 + (size_t)64 * 1024;
  const _Float16* gb0 = Wp + (size_t)(tid >> 2) * 1024 + (tid & 3) * 8;
  const _Float16* gb1 = gb0 + (size_t)64 * 1024;
  // prologue: stage k0=0 into buffer 0
  async16(ga0, &As[tid * 8]);
  async16(ga1, &As[(tid + 256) * 8]);
  async16(gb0, &Bs[tid * 8]);
  async16(gb1, &Bs[(tid + 256) * 8]);
  __syncthreads();
  for (int k0 = 0; k0 < 1024; k0 += 32) {
    const int curo = ((k0 >> 5) & 1) * (128 * 32);
    if (k0 + 32 < 1024) {
      const int nxto = (128 * 32) - curo;
      async16(ga0 + k0 + 32, &As[nxto + tid * 8]);
      async16(ga1 + k0 + 32, &As[nxto + (tid + 256) * 8]);
      async16(gb0 + k0 + 32, &Bs[nxto + tid * 8]);
      async16(gb1 + k0 + 32, &Bs[nxto + (tid + 256) * 8]);
    }
    half8 af[4], bf[4];
#pragma unroll
    for (int i = 0; i < 4; ++i)
      af[i] = *(const half8*)&As[curo + (wm0 + i * 16 + c) * 32 + quad * 8];
#pragma unroll
    for (int j = 0; j < 4; ++j)
      bf[j] = *(const half8*)&Bs[curo + (wn0 + j * 16 + c) * 32 + quad * 8];
#pragma unroll
    for (int i = 0; i < 4; ++i)
#pragma unroll
      for (int j = 0; j < 4; ++j)
        acc[i][j] = __builtin_amdgcn_mfma_f32_16x16x32_f16(af[i], bf[j], acc[i][j], 0, 0, 0);
    __syncthreads();  // drains next-tile loads (issued a full compute phase ago)
  }
}

// ---------------- QKV projection ----------------
// z=0/1: scatter to (B,H,T,64); z=2: V stored directly TRANSPOSED (B,H,64,T).
__global__ __launch_bounds__(256, 2) void gemm_qkv(
    const _Float16* __restrict__ A,
    const _Float16* __restrict__ Wq, const _Float16* __restrict__ Wk,
    const _Float16* __restrict__ Wv,
    const float* __restrict__ Bq, const float* __restrict__ Bk,
    const float* __restrict__ Bv,
    _Float16* __restrict__ Qo, _Float16* __restrict__ Ko, _Float16* __restrict__ VoT) {
  __shared__ __align__(16) _Float16 As[2 * 128 * 32];
  __shared__ __align__(16) _Float16 Bs[2 * 128 * 32];
  const int z = blockIdx.z;
  const _Float16* W = (z == 0) ? Wq : (z == 1) ? Wk : Wv;
  const float* bias = (z == 0) ? Bq : (z == 1) ? Bk : Bv;
  const float scale = (z == 0) ? LOG2E : 1.0f;  // fold exp->exp2 into Q
  const int m0 = blockIdx.x * 128, n0 = blockIdx.y * 128;
  f32x4 acc[4][4] = {};
  gemm128_mainloop(A + (size_t)m0 * 1024, W + (size_t)n0 * 1024, As, Bs, acc);
  const int tid = threadIdx.x;
  const int lane = tid & 63, wid = tid >> 6;
  const int c = lane & 15, quad = lane >> 4;
  const int wm0 = (wid >> 1) * 64, wn0 = (wid & 1) * 64;
  if (z == 2) {
#pragma unroll
    for (int j = 0; j < 4; ++j) {
      int n = n0 + wn0 + j * 16 + c;
      float bvv = bias[n];
      int h = n >> 6, d = n & 63;
#pragma unroll
      for (int i = 0; i < 4; ++i) {
        int mb = m0 + wm0 + i * 16 + quad * 4;
        int bb = mb >> 12, t = mb & 4095;
        half4_t hv;
#pragma unroll
        for (int r = 0; r < 4; ++r) hv[r] = (_Float16)(acc[i][j][r] + bvv);
        *(half4_t*)&VoT[(((size_t)((bb * 16 + h) * 64 + d)) << 12) + t] = hv;
      }
    }
  } else {
    _Float16* out = (z == 0) ? Qo : Ko;
#pragma unroll
    for (int j = 0; j < 4; ++j) {
      int n = n0 + wn0 + j * 16 + c;
      float bvv = bias[n];
      int h = n >> 6, d = n & 63;
#pragma unroll
      for (int i = 0; i < 4; ++i) {
        int mb = m0 + wm0 + i * 16 + quad * 4;
#pragma unroll
        for (int r = 0; r < 4; ++r) {
          int m = mb + r;
          float v = (acc[i][j][r] + bvv) * scale;
          int bb = m >> 12, t = m & 4095;
          out[(((size_t)(bb * 16 + h) * 4096 + t) << 6) + d] = (_Float16)v;
        }
      }
    }
  }
}

// ---------------- out projection, fp32 epilogue ----------------
__global__ __launch_bounds__(256, 2) void gemm_out(
    const _Float16* __restrict__ A, const _Float16* __restrict__ W,
    const float* __restrict__ bias, float* __restrict__ out) {
  __shared__ __align__(16) _Float16 As[2 * 128 * 32];
  __shared__ __align__(16) _Float16 Bs[2 * 128 * 32];
  const int m0 = blockIdx.x * 128, n0 = blockIdx.y * 128;
  f32x4 acc[4][4] = {};
  gemm128_mainloop(A + (size_t)m0 * 1024, W + (size_t)n0 * 1024, As, Bs, acc);
  const int tid = threadIdx.x;
  const int lane = tid & 63, wid = tid >> 6;
  const int c = lane & 15, quad = lane >> 4;
  const int wm0 = (wid >> 1) * 64, wn0 = (wid & 1) * 64;
#pragma unroll
  for (int j = 0; j < 4; ++j) {
    int n = n0 + wn0 + j * 16 + c;
    float bv = bias[n];
#pragma unroll
    for (int i = 0; i < 4; ++i) {
      int mb = m0 + wm0 + i * 16 + quad * 4;
#pragma unroll
      for (int r = 0; r < 4; ++r) {
        int m = mb + r;
        out[(size_t)m * 1024 + n] = acc[i][j][r] + bv;
      }
    }
  }
}

// ---------------- fused flash attention (buggy-variant-faithful) ----------------
// Round-4: P transpose (QK^T C/D layout -> PV A-operand layout) done entirely
// in registers via permlane32_swap+permlane16_swap (T12 generalized):
//   lane (c,quad) reg r of S holds P[q=c][key=16*j8+4*quad+r]; packing reg
//   pairs into half2 words W0..W3 and doing plswap32(W0,W2), plswap32(W1,W3),
//   plswap16(W0,W2), plswap16(W1,W3) yields exactly A[q=c][key=8*quad+e].
// This deletes the 20KB Pc buffer + all its DS traffic/bank conflicts:
// LDS 52K -> 32K -> up to 5 blocks/CU (occupancy ceiling 37.5% -> ~60%).
// Keeps: KVBLK=128 (semantics: running-max sequence matches reference BKV
// scan), XCD swizzle, coalesced epilogue, raw exp2.
__global__ __launch_bounds__(256, 5) void fa_kernel(
    const _Float16* __restrict__ Qg, const _Float16* __restrict__ Kg,
    const _Float16* __restrict__ VgT, _Float16* __restrict__ Og) {
  __shared__ __align__(16) _Float16 Ks[128 * 64];    // Q staging, then K (key, d); O staging at epilogue
  __shared__ __align__(16) _Float16 VsT[64 * 128];   // (d, key), swizzled

  const int tid = threadIdx.x;
  const int lane = tid & 63, wid = tid >> 6;
  const int c = lane & 15, quad = lane >> 4;
  // XCD-aware remap: xcd = bid&7 gets swz in [xcd*256, xcd*256+256) =
  // heads [xcd*8, xcd*8+8), all 32 qt each. Bijective (2048 % 8 == 0).
  const int bid = blockIdx.x;
  const int swz = (bid & 7) * 256 + (bid >> 3);
  const int bh = swz >> 5, qt = swz & 31;
  const int b = bh >> 4, h = bh & 15;
  const size_t hoff = (size_t)bh * 4096 * 64;
  const _Float16* Qh = Qg + hoff + (size_t)qt * 128 * 64;
  const _Float16* Kh = Kg + hoff;
  const _Float16* Vh = VgT + hoff;  // (64, 4096)

  // stage Q tile (128x64) into Ks, per-row chunk swizzle
#pragma unroll
  for (int it = 0; it < 4; ++it) {
    int cidx = it * 256 + tid;
    int row = cidx >> 3, ck = (cidx & 7) ^ (row & 7);
    async16(Qh + row * 64 + ck * 8, &Ks[cidx * 8]);
  }
  __syncthreads();

  const int wq0 = wid * 32;
  half8 qf[2][2];
#pragma unroll
  for (int i = 0; i < 2; ++i)
#pragma unroll
    for (int kk = 0; kk < 2; ++kk) {
      int row = wq0 + i * 16 + c;
      int ck = (kk * 4 + quad) ^ (c & 7);
      qf[i][kk] = *(const half8*)&Ks[row * 64 + ck * 8];
    }

  f32x4 oacc[2][4] = {};
  float M[2] = {-__builtin_inff(), -__builtin_inff()};
  float L[2] = {0.f, 0.f};

  for (int j = 0; j < 32; ++j) {
    __syncthreads();  // prior iter's Ks/VsT reads done (and Q-frag reads on j==0)
#pragma unroll
    for (int it = 0; it < 4; ++it) {
      int cidx = it * 256 + tid;
      int row = cidx >> 3, ck = (cidx & 7) ^ (row & 7);
      async16(Kh + (size_t)(j * 128 + row) * 64 + ck * 8, &Ks[cidx * 8]);
    }
#pragma unroll
    for (int it = 0; it < 4; ++it) {
      int cidx = it * 256 + tid;
      int d = cidx >> 4, ck = (cidx & 15) ^ (d & 7);
      async16(Vh + (size_t)d * 4096 + j * 128 + ck * 8, &VsT[cidx * 8]);
    }
    __syncthreads();

    // S^T = K * Q^T for both q-tiles; sacc held in regs until exp phase
    f32x4 s0[8], s1[8];
#pragma unroll
    for (int j8 = 0; j8 < 8; ++j8) {
      int krow = j8 * 16 + c;
      int ck = quad ^ (c & 7);
      half8 kf = *(const half8*)&Ks[krow * 64 + ck * 8];
      f32x4 z = {};
      s0[j8] = __builtin_amdgcn_mfma_f32_16x16x32_f16(kf, qf[0][0], z, 0, 0, 0);
      s1[j8] = __builtin_amdgcn_mfma_f32_16x16x32_f16(kf, qf[1][0], z, 0, 0, 0);
    }
#pragma unroll
    for (int j8 = 0; j8 < 8; ++j8) {
      int krow = j8 * 16 + c;
      int ck = (4 + quad) ^ (c & 7);
      half8 kf = *(const half8*)&Ks[krow * 64 + ck * 8];
      s0[j8] = __builtin_amdgcn_mfma_f32_16x16x32_f16(kf, qf[0][1], s0[j8], 0, 0, 0);
      s1[j8] = __builtin_amdgcn_mfma_f32_16x16x32_f16(kf, qf[1][1], s1[j8], 0, 0, 0);
    }

    // running max per q-tile (max3 tree + cross-quad)
    float Mn[2], al[2];
#pragma unroll
    for (int i = 0; i < 2; ++i) {
      f32x4* s = i ? s1 : s0;
      f32x4 t0 = vmax4_3(s[0], s[1], s[2]);
      f32x4 t1 = vmax4_3(s[3], s[4], s[5]);
      f32x4 t2 = vmax4_3(t0, t1, vmax4(s[6], s[7]));
      float mx = fmaxf(fmaxf(fmaxf(t2[0], t2[1]), t2[2]), t2[3]);
      mx = fmaxf(mx, __shfl_xor(mx, 16));
      mx = fmaxf(mx, __shfl_xor(mx, 32));
      Mn[i] = fmaxf(M[i], mx);
      al[i] = fexp2(M[i] - Mn[i]);
      M[i] = Mn[i];
    }

    // exp + pack + in-register transpose (permlane) + PV, 32 keys per chunk
    f32x4 rs4[2] = {};
#pragma unroll
    for (int ks = 0; ks < 4; ++ks) {
      half8 pf[2];
#pragma unroll
      for (int i = 0; i < 2; ++i) {
        f32x4* s = i ? s1 : s0;
        float mn = Mn[i];
        f32x4 a0 = s[2 * ks] - mn;
        f32x4 a1 = s[2 * ks + 1] - mn;
        f32x4 p0, p1;
        p0[0] = fexp2(a0[0]); p0[1] = fexp2(a0[1]);
        p0[2] = fexp2(a0[2]); p0[3] = fexp2(a0[3]);
        p1[0] = fexp2(a1[0]); p1[1] = fexp2(a1[1]);
        p1[2] = fexp2(a1[2]); p1[3] = fexp2(a1[3]);
        rs4[i] += p0;
        rs4[i] += p1;
        unsigned w0 = __builtin_bit_cast(unsigned, pk_cvt(p0[0], p0[1]));
        unsigned w1 = __builtin_bit_cast(unsigned, pk_cvt(p0[2], p0[3]));
        unsigned w2 = __builtin_bit_cast(unsigned, pk_cvt(p1[0], p1[1]));
        unsigned w3 = __builtin_bit_cast(unsigned, pk_cvt(p1[2], p1[3]));
        plswap32(w0, w2);
        plswap32(w1, w3);
        plswap16(w0, w2);
        plswap16(w1, w3);
        uint4_t uw = {w0, w1, w2, w3};
        pf[i] = __builtin_bit_cast(half8, uw);
      }
#pragma unroll
      for (int n = 0; n < 4; ++n) {
        int d = n * 16 + c;
        int ck = (ks * 4 + quad) ^ (d & 7);
        half8 vf = *(const half8*)&VsT[d * 128 + ck * 8];
        oacc[0][n] = __builtin_amdgcn_mfma_f32_16x16x32_f16(pf[0], vf, oacc[0][n], 0, 0, 0);
        oacc[1][n] = __builtin_amdgcn_mfma_f32_16x16x32_f16(pf[1], vf, oacc[1][n], 0, 0, 0);
      }
    }

#pragma unroll
    for (int i = 0; i < 2; ++i) {
      float rs = (rs4[i][0] + rs4[i][1]) + (rs4[i][2] + rs4[i][3]);
      rs += __shfl_xor(rs, 16);
      rs += __shfl_xor(rs, 32);
      L[i] = al[i] * L[i] + rs;  // L IS rescaled; O is NOT (faithful to reference)
    }
  }

  // ---- epilogue: O/L, staged through Ks for coalesced 128B-row stores ----
  __syncthreads();  // all waves done reading Ks/VsT before Ks is reused
#pragma unroll
  for (int i = 0; i < 2; ++i) {
#pragma unroll
    for (int r = 0; r < 4; ++r) {
      float Lq = __shfl(L[i], quad * 4 + r);
      float inv = 1.0f / Lq;
      int row = wq0 + i * 16 + quad * 4 + r;
#pragma unroll
      for (int n = 0; n < 4; ++n)
        Ks[row * 64 + n * 16 + c] = (_Float16)(oacc[i][n][r] * inv);
    }
  }
  __syncthreads();
  {
    int row = tid >> 1, hf = tid & 1;
    int t = qt * 128 + row;
    size_t base = (((size_t)(b * 4096 + t)) << 10) + h * 64 + hf * 32;
    const half8* srcp = (const half8*)&Ks[row * 64 + hf * 32];
    half8* dstp = (half8*)(Og + base);
    dstp[0] = srcp[0];
    dstp[1] = srcp[1];
    dstp[2] = srcp[2];
    dstp[3] = srcp[3];
  }
}

// ---------------- launcher ----------------
extern "C" void kernel_launch(void* const* d_in, const int* in_sizes, int n_in,
                              void* d_out, int out_size, void* d_ws, size_t ws_size,
                              hipStream_t stream) {
  const float* x = (const float*)d_in[0];
  const float* wq = (const float*)d_in[1];
  const float* bq = (const float*)d_in[2];
  const float* wk = (const float*)d_in[3];
  const float* bk = (const float*)d_in[4];
  const float* wv = (const float*)d_in[5];
  const float* bv = (const float*)d_in[6];
  const float* wo = (const float*)d_in[7];
  const float* bo = (const float*)d_in[8];

  char* ws = (char*)d_ws;
  const size_t MB = 1024 * 1024;
  _Float16* xb = (_Float16*)(ws);               // 32MB; dead after gemm_qkv -> reused as Oatt
  _Float16* wq16 = (_Float16*)(ws + 32 * MB);
  _Float16* wk16 = (_Float16*)(ws + 34 * MB);
  _Float16* wv16 = (_Float16*)(ws + 36 * MB);
  _Float16* wo16 = (_Float16*)(ws + 38 * MB);
  _Float16* Qg = (_Float16*)(ws + 40 * MB);     // (B,H,T,64)
  _Float16* Kg = (_Float16*)(ws + 72 * MB);     // (B,H,T,64)
  _Float16* VgT = (_Float16*)(ws + 104 * MB);   // (B,H,64,T) written directly by gemm_qkv
  _Float16* Oatt = xb;                          // (B,T,1024)

  cvt_f32_f16<<<8192, 256, 0, stream>>>(x, xb, 16777216);
  cvt_w4<<<2048, 256, 0, stream>>>(wq, wk, wv, wo, wq16, wk16, wv16, wo16);

  gemm_qkv<<<dim3(128, 8, 3), 256, 0, stream>>>(xb, wq16, wk16, wv16,
                                                bq, bk, bv, Qg, Kg, VgT);
  fa_kernel<<<dim3(2048), 256, 0, stream>>>(Qg, Kg, VgT, Oatt);
  gemm_out<<<dim3(128, 8), 256, 0, stream>>>(Oatt, wo16, bo, (float*)d_out);
}

// Round 6
// 918.032 us; speedup vs baseline: 1.5877x; 1.5877x over previous
//
#include <hip/hip_runtime.h>
#include <cstdint>
#include <cstddef>

typedef _Float16 half8 __attribute__((ext_vector_type(8)));
typedef _Float16 half4_t __attribute__((ext_vector_type(4)));
typedef _Float16 half2_t __attribute__((ext_vector_type(2)));
typedef float f32x4 __attribute__((ext_vector_type(4)));
typedef unsigned int uint4_t __attribute__((ext_vector_type(4)));
typedef unsigned int uint2_t __attribute__((ext_vector_type(2)));

#define LOG2E 1.4426950408889634f

// async global->LDS, 16B per lane. LDS dest must be wave-uniform base + lane*16.
__device__ __forceinline__ void async16(const void* g, void* l) {
  __builtin_amdgcn_global_load_lds((const __attribute__((address_space(1))) void*)g,
                                   (__attribute__((address_space(3))) void*)l,
                                   16, 0, 0);
}

__device__ __forceinline__ f32x4 vmax4(f32x4 a, f32x4 b) {
  f32x4 r;
  r[0] = fmaxf(a[0], b[0]); r[1] = fmaxf(a[1], b[1]);
  r[2] = fmaxf(a[2], b[2]); r[3] = fmaxf(a[3], b[3]);
  return r;
}

// fmaxf(fmaxf(a,b),c) fuses to v_max3_f32
__device__ __forceinline__ f32x4 vmax4_3(f32x4 a, f32x4 b, f32x4 c) {
  f32x4 r;
  r[0] = fmaxf(fmaxf(a[0], b[0]), c[0]);
  r[1] = fmaxf(fmaxf(a[1], b[1]), c[1]);
  r[2] = fmaxf(fmaxf(a[2], b[2]), c[2]);
  r[3] = fmaxf(fmaxf(a[3], b[3]), c[3]);
  return r;
}

__device__ __forceinline__ half2_t pk_cvt(float a, float b) {
  return __builtin_bit_cast(half2_t, __builtin_amdgcn_cvt_pkrtz(a, b));
}

// raw v_exp_f32 (skips OCML denormal fixup; args are <= 0, outputs in [0,1])
__device__ __forceinline__ float fexp2(float x) { return __builtin_amdgcn_exp2f(x); }

// gfx950 cross-lane swaps via BUILTINS (not inline asm!).
// r5 lesson: the raw `asm("v_permlane32_swap_b32 ...")` version is schedule-
// dependent-broken — the permlane ops have a VALU-write->permlane-read hazard
// that the backend's hazard recognizer handles only for known MIs; an asm blob
// is opaque, so under the tight (256,4) spill-free schedule the v_cvt_pkrtz
// results fed the swap with no wait states and lanes read stale data (r4's
// spill-heavy schedule masked it by accident). The builtins emit real MIs so
// the compiler inserts the required waits under any schedule.
// Semantics: new_a = {a.lo32lanes, b.lo32lanes}, new_b = {a.hi32lanes, b.hi32lanes}
// (permlane32); analogous 16-lane-row exchange for permlane16.
__device__ __forceinline__ void plswap32(unsigned& a, unsigned& b) {
  uint2_t r = __builtin_amdgcn_permlane32_swap(a, b, false, false);
  a = r[0]; b = r[1];
}
__device__ __forceinline__ void plswap16(unsigned& a, unsigned& b) {
  uint2_t r = __builtin_amdgcn_permlane16_swap(a, b, false, false);
  a = r[0]; b = r[1];
}

// ---------------- fp32 -> fp16 convert ----------------
__global__ __launch_bounds__(256) void cvt_f32_f16(const float* __restrict__ in,
                                                   _Float16* __restrict__ out, int n) {
  int i = (blockIdx.x * 256 + threadIdx.x) * 8;
  if (i + 7 < n) {
    f32x4 a = *(const f32x4*)(in + i);
    f32x4 b = *(const f32x4*)(in + i + 4);
    half8 h;
    h[0] = (_Float16)a[0]; h[1] = (_Float16)a[1];
    h[2] = (_Float16)a[2]; h[3] = (_Float16)a[3];
    h[4] = (_Float16)b[0]; h[5] = (_Float16)b[1];
    h[6] = (_Float16)b[2]; h[7] = (_Float16)b[3];
    *(half8*)(out + i) = h;
  }
}

// 4 weight matrices (1M elems each) in one launch
__global__ __launch_bounds__(256) void cvt_w4(
    const float* __restrict__ a, const float* __restrict__ b,
    const float* __restrict__ c, const float* __restrict__ d,
    _Float16* __restrict__ oa, _Float16* __restrict__ ob,
    _Float16* __restrict__ oc, _Float16* __restrict__ od) {
  int seg = blockIdx.x >> 9;
  const float* src = (seg == 0) ? a : (seg == 1) ? b : (seg == 2) ? c : d;
  _Float16* dst = (seg == 0) ? oa : (seg == 1) ? ob : (seg == 2) ? oc : od;
  int i = ((blockIdx.x & 511) * 256 + threadIdx.x) * 8;
  f32x4 x0 = *(const f32x4*)(src + i);
  f32x4 x1 = *(const f32x4*)(src + i + 4);
  half8 h;
  h[0] = (_Float16)x0[0]; h[1] = (_Float16)x0[1];
  h[2] = (_Float16)x0[2]; h[3] = (_Float16)x0[3];
  h[4] = (_Float16)x1[0]; h[5] = (_Float16)x1[1];
  h[6] = (_Float16)x1[2]; h[7] = (_Float16)x1[3];
  *(half8*)(dst + i) = h;
}

// ---------------- shared 128x128x1024 NT-GEMM mainloop ----------------
// Double-buffered LDS, issue-early / sync-late (T3-minimum pipeline).
__device__ __forceinline__ void gemm128_mainloop(const _Float16* __restrict__ Ap,
                                                 const _Float16* __restrict__ Wp,
                                                 _Float16* As, _Float16* Bs,
                                                 f32x4 (&acc)[4][4]) {
  const int tid = threadIdx.x;
  const int lane = tid & 63;
  const int wid = tid >> 6;
  const int c = lane & 15, quad = lane >> 4;
  const int wm0 = (wid >> 1) * 64, wn0 = (wid & 1) * 64;
  const _Float16* ga0 = Ap + (size_t)(tid >> 2) * 1024 + (tid & 3) * 8;
  const _Float16* ga1 = ga0 + (size_t)64 * 1024;
  const _Float16* gb0 = Wp + (size_t)(tid >> 2) * 1024 + (tid & 3) * 8;
  const _Float16* gb1 = gb0 + (size_t)64 * 1024;
  // prologue: stage k0=0 into buffer 0
  async16(ga0, &As[tid * 8]);
  async16(ga1, &As[(tid + 256) * 8]);
  async16(gb0, &Bs[tid * 8]);
  async16(gb1, &Bs[(tid + 256) * 8]);
  __syncthreads();
  for (int k0 = 0; k0 < 1024; k0 += 32) {
    const int curo = ((k0 >> 5) & 1) * (128 * 32);
    if (k0 + 32 < 1024) {
      const int nxto = (128 * 32) - curo;
      async16(ga0 + k0 + 32, &As[nxto + tid * 8]);
      async16(ga1 + k0 + 32, &As[nxto + (tid + 256) * 8]);
      async16(gb0 + k0 + 32, &Bs[nxto + tid * 8]);
      async16(gb1 + k0 + 32, &Bs[nxto + (tid + 256) * 8]);
    }
    half8 af[4], bf[4];
#pragma unroll
    for (int i = 0; i < 4; ++i)
      af[i] = *(const half8*)&As[curo + (wm0 + i * 16 + c) * 32 + quad * 8];
#pragma unroll
    for (int j = 0; j < 4; ++j)
      bf[j] = *(const half8*)&Bs[curo + (wn0 + j * 16 + c) * 32 + quad * 8];
#pragma unroll
    for (int i = 0; i < 4; ++i)
#pragma unroll
      for (int j = 0; j < 4; ++j)
        acc[i][j] = __builtin_amdgcn_mfma_f32_16x16x32_f16(af[i], bf[j], acc[i][j], 0, 0, 0);
    __syncthreads();  // drains next-tile loads (issued a full compute phase ago)
  }
}

// ---------------- QKV projection ----------------
// z=0/1: scatter to (B,H,T,64); z=2: V stored directly TRANSPOSED (B,H,64,T).
__global__ __launch_bounds__(256, 2) void gemm_qkv(
    const _Float16* __restrict__ A,
    const _Float16* __restrict__ Wq, const _Float16* __restrict__ Wk,
    const _Float16* __restrict__ Wv,
    const float* __restrict__ Bq, const float* __restrict__ Bk,
    const float* __restrict__ Bv,
    _Float16* __restrict__ Qo, _Float16* __restrict__ Ko, _Float16* __restrict__ VoT) {
  __shared__ __align__(16) _Float16 As[2 * 128 * 32];
  __shared__ __align__(16) _Float16 Bs[2 * 128 * 32];
  const int z = blockIdx.z;
  const _Float16* W = (z == 0) ? Wq : (z == 1) ? Wk : Wv;
  const float* bias = (z == 0) ? Bq : (z == 1) ? Bk : Bv;
  const float scale = (z == 0) ? LOG2E : 1.0f;  // fold exp->exp2 into Q
  const int m0 = blockIdx.x * 128, n0 = blockIdx.y * 128;
  f32x4 acc[4][4] = {};
  gemm128_mainloop(A + (size_t)m0 * 1024, W + (size_t)n0 * 1024, As, Bs, acc);
  const int tid = threadIdx.x;
  const int lane = tid & 63, wid = tid >> 6;
  const int c = lane & 15, quad = lane >> 4;
  const int wm0 = (wid >> 1) * 64, wn0 = (wid & 1) * 64;
  if (z == 2) {
#pragma unroll
    for (int j = 0; j < 4; ++j) {
      int n = n0 + wn0 + j * 16 + c;
      float bvv = bias[n];
      int h = n >> 6, d = n & 63;
#pragma unroll
      for (int i = 0; i < 4; ++i) {
        int mb = m0 + wm0 + i * 16 + quad * 4;
        int bb = mb >> 12, t = mb & 4095;
        half4_t hv;
#pragma unroll
        for (int r = 0; r < 4; ++r) hv[r] = (_Float16)(acc[i][j][r] + bvv);
        *(half4_t*)&VoT[(((size_t)((bb * 16 + h) * 64 + d)) << 12) + t] = hv;
      }
    }
  } else {
    _Float16* out = (z == 0) ? Qo : Ko;
#pragma unroll
    for (int j = 0; j < 4; ++j) {
      int n = n0 + wn0 + j * 16 + c;
      float bvv = bias[n];
      int h = n >> 6, d = n & 63;
#pragma unroll
      for (int i = 0; i < 4; ++i) {
        int mb = m0 + wm0 + i * 16 + quad * 4;
#pragma unroll
        for (int r = 0; r < 4; ++r) {
          int m = mb + r;
          float v = (acc[i][j][r] + bvv) * scale;
          int bb = m >> 12, t = m & 4095;
          out[(((size_t)(bb * 16 + h) * 4096 + t) << 6) + d] = (_Float16)v;
        }
      }
    }
  }
}

// ---------------- out projection, fp32 epilogue ----------------
__global__ __launch_bounds__(256, 2) void gemm_out(
    const _Float16* __restrict__ A, const _Float16* __restrict__ W,
    const float* __restrict__ bias, float* __restrict__ out) {
  __shared__ __align__(16) _Float16 As[2 * 128 * 32];
  __shared__ __align__(16) _Float16 Bs[2 * 128 * 32];
  const int m0 = blockIdx.x * 128, n0 = blockIdx.y * 128;
  f32x4 acc[4][4] = {};
  gemm128_mainloop(A + (size_t)m0 * 1024, W + (size_t)n0 * 1024, As, Bs, acc);
  const int tid = threadIdx.x;
  const int lane = tid & 63, wid = tid >> 6;
  const int c = lane & 15, quad = lane >> 4;
  const int wm0 = (wid >> 1) * 64, wn0 = (wid & 1) * 64;
#pragma unroll
  for (int j = 0; j < 4; ++j) {
    int n = n0 + wn0 + j * 16 + c;
    float bv = bias[n];
#pragma unroll
    for (int i = 0; i < 4; ++i) {
      int mb = m0 + wm0 + i * 16 + quad * 4;
#pragma unroll
      for (int r = 0; r < 4; ++r) {
        int m = mb + r;
        out[(size_t)m * 1024 + n] = acc[i][j][r] + bv;
      }
    }
  }
}

// ---------------- fused flash attention (buggy-variant-faithful) ----------------
// In-register P transpose via permlane builtins (hazard-safe; see plswap note).
// LDS 32K. launch_bounds(256,4): 128-VGPR budget fits the ~100-reg live set
// (s0/s1=64, oacc=32, qf=16 overlapping addressing) spill-free; LDS allows 5
// blocks/CU, VGPR caps at 4 -> 50% occupancy ceiling (vs r3's 37.5%).
// Keeps: KVBLK=128 (semantics: running-max sequence matches reference BKV
// scan), XCD swizzle, coalesced epilogue, raw exp2.
__global__ __launch_bounds__(256, 4) void fa_kernel(
    const _Float16* __restrict__ Qg, const _Float16* __restrict__ Kg,
    const _Float16* __restrict__ VgT, _Float16* __restrict__ Og) {
  __shared__ __align__(16) _Float16 Ks[128 * 64];    // Q staging, then K (key, d); O staging at epilogue
  __shared__ __align__(16) _Float16 VsT[64 * 128];   // (d, key), swizzled

  const int tid = threadIdx.x;
  const int lane = tid & 63, wid = tid >> 6;
  const int c = lane & 15, quad = lane >> 4;
  // XCD-aware remap: xcd = bid&7 gets swz in [xcd*256, xcd*256+256) =
  // heads [xcd*8, xcd*8+8), all 32 qt each. Bijective (2048 % 8 == 0).
  const int bid = blockIdx.x;
  const int swz = (bid & 7) * 256 + (bid >> 3);
  const int bh = swz >> 5, qt = swz & 31;
  const int b = bh >> 4, h = bh & 15;
  const size_t hoff = (size_t)bh * 4096 * 64;
  const _Float16* Qh = Qg + hoff + (size_t)qt * 128 * 64;
  const _Float16* Kh = Kg + hoff;
  const _Float16* Vh = VgT + hoff;  // (64, 4096)

  // stage Q tile (128x64) into Ks, per-row chunk swizzle
#pragma unroll
  for (int it = 0; it < 4; ++it) {
    int cidx = it * 256 + tid;
    int row = cidx >> 3, ck = (cidx & 7) ^ (row & 7);
    async16(Qh + row * 64 + ck * 8, &Ks[cidx * 8]);
  }
  __syncthreads();

  const int wq0 = wid * 32;
  half8 qf[2][2];
#pragma unroll
  for (int i = 0; i < 2; ++i)
#pragma unroll
    for (int kk = 0; kk < 2; ++kk) {
      int row = wq0 + i * 16 + c;
      int ck = (kk * 4 + quad) ^ (c & 7);
      qf[i][kk] = *(const half8*)&Ks[row * 64 + ck * 8];
    }

  f32x4 oacc[2][4] = {};
  float M[2] = {-__builtin_inff(), -__builtin_inff()};
  float L[2] = {0.f, 0.f};

  for (int j = 0; j < 32; ++j) {
    __syncthreads();  // prior iter's Ks/VsT reads done (and Q-frag reads on j==0)
#pragma unroll
    for (int it = 0; it < 4; ++it) {
      int cidx = it * 256 + tid;
      int row = cidx >> 3, ck = (cidx & 7) ^ (row & 7);
      async16(Kh + (size_t)(j * 128 + row) * 64 + ck * 8, &Ks[cidx * 8]);
    }
#pragma unroll
    for (int it = 0; it < 4; ++it) {
      int cidx = it * 256 + tid;
      int d = cidx >> 4, ck = (cidx & 15) ^ (d & 7);
      async16(Vh + (size_t)d * 4096 + j * 128 + ck * 8, &VsT[cidx * 8]);
    }
    __syncthreads();

    // S^T = K * Q^T for both q-tiles; sacc held in regs until exp phase
    f32x4 s0[8], s1[8];
#pragma unroll
    for (int j8 = 0; j8 < 8; ++j8) {
      int krow = j8 * 16 + c;
      int ck = quad ^ (c & 7);
      half8 kf = *(const half8*)&Ks[krow * 64 + ck * 8];
      f32x4 z = {};
      s0[j8] = __builtin_amdgcn_mfma_f32_16x16x32_f16(kf, qf[0][0], z, 0, 0, 0);
      s1[j8] = __builtin_amdgcn_mfma_f32_16x16x32_f16(kf, qf[1][0], z, 0, 0, 0);
    }
#pragma unroll
    for (int j8 = 0; j8 < 8; ++j8) {
      int krow = j8 * 16 + c;
      int ck = (4 + quad) ^ (c & 7);
      half8 kf = *(const half8*)&Ks[krow * 64 + ck * 8];
      s0[j8] = __builtin_amdgcn_mfma_f32_16x16x32_f16(kf, qf[0][1], s0[j8], 0, 0, 0);
      s1[j8] = __builtin_amdgcn_mfma_f32_16x16x32_f16(kf, qf[1][1], s1[j8], 0, 0, 0);
    }

    // running max per q-tile (max3 tree + cross-quad)
    float Mn[2], al[2];
#pragma unroll
    for (int i = 0; i < 2; ++i) {
      f32x4* s = i ? s1 : s0;
      f32x4 t0 = vmax4_3(s[0], s[1], s[2]);
      f32x4 t1 = vmax4_3(s[3], s[4], s[5]);
      f32x4 t2 = vmax4_3(t0, t1, vmax4(s[6], s[7]));
      float mx = fmaxf(fmaxf(fmaxf(t2[0], t2[1]), t2[2]), t2[3]);
      mx = fmaxf(mx, __shfl_xor(mx, 16));
      mx = fmaxf(mx, __shfl_xor(mx, 32));
      Mn[i] = fmaxf(M[i], mx);
      al[i] = fexp2(M[i] - Mn[i]);
      M[i] = Mn[i];
    }

    // exp + pack + in-register transpose (permlane) + PV, 32 keys per chunk
    f32x4 rs4[2] = {};
#pragma unroll
    for (int ks = 0; ks < 4; ++ks) {
      half8 pf[2];
#pragma unroll
      for (int i = 0; i < 2; ++i) {
        f32x4* s = i ? s1 : s0;
        float mn = Mn[i];
        f32x4 a0 = s[2 * ks] - mn;
        f32x4 a1 = s[2 * ks + 1] - mn;
        f32x4 p0, p1;
        p0[0] = fexp2(a0[0]); p0[1] = fexp2(a0[1]);
        p0[2] = fexp2(a0[2]); p0[3] = fexp2(a0[3]);
        p1[0] = fexp2(a1[0]); p1[1] = fexp2(a1[1]);
        p1[2] = fexp2(a1[2]); p1[3] = fexp2(a1[3]);
        rs4[i] += p0;
        rs4[i] += p1;
        unsigned w0 = __builtin_bit_cast(unsigned, pk_cvt(p0[0], p0[1]));
        unsigned w1 = __builtin_bit_cast(unsigned, pk_cvt(p0[2], p0[3]));
        unsigned w2 = __builtin_bit_cast(unsigned, pk_cvt(p1[0], p1[1]));
        unsigned w3 = __builtin_bit_cast(unsigned, pk_cvt(p1[2], p1[3]));
        plswap32(w0, w2);
        plswap32(w1, w3);
        plswap16(w0, w2);
        plswap16(w1, w3);
        uint4_t uw = {w0, w1, w2, w3};
        pf[i] = __builtin_bit_cast(half8, uw);
      }
#pragma unroll
      for (int n = 0; n < 4; ++n) {
        int d = n * 16 + c;
        int ck = (ks * 4 + quad) ^ (d & 7);
        half8 vf = *(const half8*)&VsT[d * 128 + ck * 8];
        oacc[0][n] = __builtin_amdgcn_mfma_f32_16x16x32_f16(pf[0], vf, oacc[0][n], 0, 0, 0);
        oacc[1][n] = __builtin_amdgcn_mfma_f32_16x16x32_f16(pf[1], vf, oacc[1][n], 0, 0, 0);
      }
    }

#pragma unroll
    for (int i = 0; i < 2; ++i) {
      float rs = (rs4[i][0] + rs4[i][1]) + (rs4[i][2] + rs4[i][3]);
      rs += __shfl_xor(rs, 16);
      rs += __shfl_xor(rs, 32);
      L[i] = al[i] * L[i] + rs;  // L IS rescaled; O is NOT (faithful to reference)
    }
  }

  // ---- epilogue: O/L, staged through Ks for coalesced 128B-row stores ----
  __syncthreads();  // all waves done reading Ks/VsT before Ks is reused
#pragma unroll
  for (int i = 0; i < 2; ++i) {
#pragma unroll
    for (int r = 0; r < 4; ++r) {
      float Lq = __shfl(L[i], quad * 4 + r);
      float inv = 1.0f / Lq;
      int row = wq0 + i * 16 + quad * 4 + r;
#pragma unroll
      for (int n = 0; n < 4; ++n)
        Ks[row * 64 + n * 16 + c] = (_Float16)(oacc[i][n][r] * inv);
    }
  }
  __syncthreads();
  {
    int row = tid >> 1, hf = tid & 1;
    int t = qt * 128 + row;
    size_t base = (((size_t)(b * 4096 + t)) << 10) + h * 64 + hf * 32;
    const half8* srcp = (const half8*)&Ks[row * 64 + hf * 32];
    half8* dstp = (half8*)(Og + base);
    dstp[0] = srcp[0];
    dstp[1] = srcp[1];
    dstp[2] = srcp[2];
    dstp[3] = srcp[3];
  }
}

// ---------------- launcher ----------------
extern "C" void kernel_launch(void* const* d_in, const int* in_sizes, int n_in,
                              void* d_out, int out_size, void* d_ws, size_t ws_size,
                              hipStream_t stream) {
  const float* x = (const float*)d_in[0];
  const float* wq = (const float*)d_in[1];
  const float* bq = (const float*)d_in[2];
  const float* wk = (const float*)d_in[3];
  const float* bk = (const float*)d_in[4];
  const float* wv = (const float*)d_in[5];
  const float* bv = (const float*)d_in[6];
  const float* wo = (const float*)d_in[7];
  const float* bo = (const float*)d_in[8];

  char* ws = (char*)d_ws;
  const size_t MB = 1024 * 1024;
  _Float16* xb = (_Float16*)(ws);               // 32MB; dead after gemm_qkv -> reused as Oatt
  _Float16* wq16 = (_Float16*)(ws + 32 * MB);
  _Float16* wk16 = (_Float16*)(ws + 34 * MB);
  _Float16* wv16 = (_Float16*)(ws + 36 * MB);
  _Float16* wo16 = (_Float16*)(ws + 38 * MB);
  _Float16* Qg = (_Float16*)(ws + 40 * MB);     // (B,H,T,64)
  _Float16* Kg = (_Float16*)(ws + 72 * MB);     // (B,H,T,64)
  _Float16* VgT = (_Float16*)(ws + 104 * MB);   // (B,H,64,T) written directly by gemm_qkv
  _Float16* Oatt = xb;                          // (B,T,1024)

  cvt_f32_f16<<<8192, 256, 0, stream>>>(x, xb, 16777216);
  cvt_w4<<<2048, 256, 0, stream>>>(wq, wk, wv, wo, wq16, wk16, wv16, wo16);

  gemm_qkv<<<dim3(128, 8, 3), 256, 0, stream>>>(xb, wq16, wk16, wv16,
                                                bq, bk, bv, Qg, Kg, VgT);
  fa_kernel<<<dim3(2048), 256, 0, stream>>>(Qg, Kg, VgT, Oatt);
  gemm_out<<<dim3(128, 8), 256, 0, stream>>>(Oatt, wo16, bo, (float*)d_out);
}

// Round 7
// 725.833 us; speedup vs baseline: 2.0081x; 1.2648x over previous
//
#include <hip/hip_runtime.h>
#include <cstdint>
#include <cstddef>

typedef _Float16 half8 __attribute__((ext_vector_type(8)));
typedef _Float16 half4_t __attribute__((ext_vector_type(4)));
typedef _Float16 half2_t __attribute__((ext_vector_type(2)));
typedef float f32x4 __attribute__((ext_vector_type(4)));
typedef unsigned int uint4_t __attribute__((ext_vector_type(4)));
typedef unsigned int uint2_t __attribute__((ext_vector_type(2)));

#define LOG2E 1.4426950408889634f

// async global->LDS, 16B per lane. LDS dest must be wave-uniform base + lane*16.
__device__ __forceinline__ void async16(const void* g, void* l) {
  __builtin_amdgcn_global_load_lds((const __attribute__((address_space(1))) void*)g,
                                   (__attribute__((address_space(3))) void*)l,
                                   16, 0, 0);
}

__device__ __forceinline__ f32x4 vmax4(f32x4 a, f32x4 b) {
  f32x4 r;
  r[0] = fmaxf(a[0], b[0]); r[1] = fmaxf(a[1], b[1]);
  r[2] = fmaxf(a[2], b[2]); r[3] = fmaxf(a[3], b[3]);
  return r;
}

// fmaxf(fmaxf(a,b),c) fuses to v_max3_f32
__device__ __forceinline__ f32x4 vmax4_3(f32x4 a, f32x4 b, f32x4 c) {
  f32x4 r;
  r[0] = fmaxf(fmaxf(a[0], b[0]), c[0]);
  r[1] = fmaxf(fmaxf(a[1], b[1]), c[1]);
  r[2] = fmaxf(fmaxf(a[2], b[2]), c[2]);
  r[3] = fmaxf(fmaxf(a[3], b[3]), c[3]);
  return r;
}

__device__ __forceinline__ half2_t pk_cvt(float a, float b) {
  return __builtin_bit_cast(half2_t, __builtin_amdgcn_cvt_pkrtz(a, b));
}

// raw v_exp_f32 (skips OCML denormal fixup; args are <= 0, outputs in [0,1])
__device__ __forceinline__ float fexp2(float x) { return __builtin_amdgcn_exp2f(x); }

// gfx950 cross-lane swaps via BUILTINS (not inline asm!).
// r5 lesson: raw asm permlane is schedule-dependent-broken (VALU->permlane
// hazard invisible through an asm blob); builtins emit real MIs so the
// backend inserts required wait states under any schedule.
__device__ __forceinline__ void plswap32(unsigned& a, unsigned& b) {
  uint2_t r = __builtin_amdgcn_permlane32_swap(a, b, false, false);
  a = r[0]; b = r[1];
}
__device__ __forceinline__ void plswap16(unsigned& a, unsigned& b) {
  uint2_t r = __builtin_amdgcn_permlane16_swap(a, b, false, false);
  a = r[0]; b = r[1];
}

// ---------------- fp32 -> fp16 convert ----------------
__global__ __launch_bounds__(256) void cvt_f32_f16(const float* __restrict__ in,
                                                   _Float16* __restrict__ out, int n) {
  int i = (blockIdx.x * 256 + threadIdx.x) * 8;
  if (i + 7 < n) {
    f32x4 a = *(const f32x4*)(in + i);
    f32x4 b = *(const f32x4*)(in + i + 4);
    half8 h;
    h[0] = (_Float16)a[0]; h[1] = (_Float16)a[1];
    h[2] = (_Float16)a[2]; h[3] = (_Float16)a[3];
    h[4] = (_Float16)b[0]; h[5] = (_Float16)b[1];
    h[6] = (_Float16)b[2]; h[7] = (_Float16)b[3];
    *(half8*)(out + i) = h;
  }
}

// 4 weight matrices (1M elems each) in one launch
__global__ __launch_bounds__(256) void cvt_w4(
    const float* __restrict__ a, const float* __restrict__ b,
    const float* __restrict__ c, const float* __restrict__ d,
    _Float16* __restrict__ oa, _Float16* __restrict__ ob,
    _Float16* __restrict__ oc, _Float16* __restrict__ od) {
  int seg = blockIdx.x >> 9;
  const float* src = (seg == 0) ? a : (seg == 1) ? b : (seg == 2) ? c : d;
  _Float16* dst = (seg == 0) ? oa : (seg == 1) ? ob : (seg == 2) ? oc : od;
  int i = ((blockIdx.x & 511) * 256 + threadIdx.x) * 8;
  f32x4 x0 = *(const f32x4*)(src + i);
  f32x4 x1 = *(const f32x4*)(src + i + 4);
  half8 h;
  h[0] = (_Float16)x0[0]; h[1] = (_Float16)x0[1];
  h[2] = (_Float16)x0[2]; h[3] = (_Float16)x0[3];
  h[4] = (_Float16)x1[0]; h[5] = (_Float16)x1[1];
  h[6] = (_Float16)x1[2]; h[7] = (_Float16)x1[3];
  *(half8*)(dst + i) = h;
}

// ---------------- shared 128x128x1024 NT-GEMM mainloop ----------------
// Double-buffered LDS, issue-early / sync-late (T3-minimum pipeline).
__device__ __forceinline__ void gemm128_mainloop(const _Float16* __restrict__ Ap,
                                                 const _Float16* __restrict__ Wp,
                                                 _Float16* As, _Float16* Bs,
                                                 f32x4 (&acc)[4][4]) {
  const int tid = threadIdx.x;
  const int lane = tid & 63;
  const int wid = tid >> 6;
  const int c = lane & 15, quad = lane >> 4;
  const int wm0 = (wid >> 1) * 64, wn0 = (wid & 1) * 64;
  const _Float16* ga0 = Ap + (size_t)(tid >> 2) * 1024 + (tid & 3) * 8;
  const _Float16* ga1 = ga0 + (size_t)64 * 1024;
  const _Float16* gb0 = Wp + (size_t)(tid >> 2) * 1024 + (tid & 3) * 8;
  const _Float16* gb1 = gb0 + (size_t)64 * 1024;
  // prologue: stage k0=0 into buffer 0
  async16(ga0, &As[tid * 8]);
  async16(ga1, &As[(tid + 256) * 8]);
  async16(gb0, &Bs[tid * 8]);
  async16(gb1, &Bs[(tid + 256) * 8]);
  __syncthreads();
  for (int k0 = 0; k0 < 1024; k0 += 32) {
    const int curo = ((k0 >> 5) & 1) * (128 * 32);
    if (k0 + 32 < 1024) {
      const int nxto = (128 * 32) - curo;
      async16(ga0 + k0 + 32, &As[nxto + tid * 8]);
      async16(ga1 + k0 + 32, &As[nxto + (tid + 256) * 8]);
      async16(gb0 + k0 + 32, &Bs[nxto + tid * 8]);
      async16(gb1 + k0 + 32, &Bs[nxto + (tid + 256) * 8]);
    }
    half8 af[4], bf[4];
#pragma unroll
    for (int i = 0; i < 4; ++i)
      af[i] = *(const half8*)&As[curo + (wm0 + i * 16 + c) * 32 + quad * 8];
#pragma unroll
    for (int j = 0; j < 4; ++j)
      bf[j] = *(const half8*)&Bs[curo + (wn0 + j * 16 + c) * 32 + quad * 8];
#pragma unroll
    for (int i = 0; i < 4; ++i)
#pragma unroll
      for (int j = 0; j < 4; ++j)
        acc[i][j] = __builtin_amdgcn_mfma_f32_16x16x32_f16(af[i], bf[j], acc[i][j], 0, 0, 0);
    __syncthreads();  // drains next-tile loads (issued a full compute phase ago)
  }
}

// ---------------- QKV projection ----------------
// z=0/1: scatter to (B,H,T,64); z=2: V stored directly TRANSPOSED (B,H,64,T).
__global__ __launch_bounds__(256, 2) void gemm_qkv(
    const _Float16* __restrict__ A,
    const _Float16* __restrict__ Wq, const _Float16* __restrict__ Wk,
    const _Float16* __restrict__ Wv,
    const float* __restrict__ Bq, const float* __restrict__ Bk,
    const float* __restrict__ Bv,
    _Float16* __restrict__ Qo, _Float16* __restrict__ Ko, _Float16* __restrict__ VoT) {
  __shared__ __align__(16) _Float16 As[2 * 128 * 32];
  __shared__ __align__(16) _Float16 Bs[2 * 128 * 32];
  const int z = blockIdx.z;
  const _Float16* W = (z == 0) ? Wq : (z == 1) ? Wk : Wv;
  const float* bias = (z == 0) ? Bq : (z == 1) ? Bk : Bv;
  const float scale = (z == 0) ? LOG2E : 1.0f;  // fold exp->exp2 into Q
  const int m0 = blockIdx.x * 128, n0 = blockIdx.y * 128;
  f32x4 acc[4][4] = {};
  gemm128_mainloop(A + (size_t)m0 * 1024, W + (size_t)n0 * 1024, As, Bs, acc);
  const int tid = threadIdx.x;
  const int lane = tid & 63, wid = tid >> 6;
  const int c = lane & 15, quad = lane >> 4;
  const int wm0 = (wid >> 1) * 64, wn0 = (wid & 1) * 64;
  if (z == 2) {
#pragma unroll
    for (int j = 0; j < 4; ++j) {
      int n = n0 + wn0 + j * 16 + c;
      float bvv = bias[n];
      int h = n >> 6, d = n & 63;
#pragma unroll
      for (int i = 0; i < 4; ++i) {
        int mb = m0 + wm0 + i * 16 + quad * 4;
        int bb = mb >> 12, t = mb & 4095;
        half4_t hv;
#pragma unroll
        for (int r = 0; r < 4; ++r) hv[r] = (_Float16)(acc[i][j][r] + bvv);
        *(half4_t*)&VoT[(((size_t)((bb * 16 + h) * 64 + d)) << 12) + t] = hv;
      }
    }
  } else {
    _Float16* out = (z == 0) ? Qo : Ko;
#pragma unroll
    for (int j = 0; j < 4; ++j) {
      int n = n0 + wn0 + j * 16 + c;
      float bvv = bias[n];
      int h = n >> 6, d = n & 63;
#pragma unroll
      for (int i = 0; i < 4; ++i) {
        int mb = m0 + wm0 + i * 16 + quad * 4;
#pragma unroll
        for (int r = 0; r < 4; ++r) {
          int m = mb + r;
          float v = (acc[i][j][r] + bvv) * scale;
          int bb = m >> 12, t = m & 4095;
          out[(((size_t)(bb * 16 + h) * 4096 + t) << 6) + d] = (_Float16)v;
        }
      }
    }
  }
}

// ---------------- out projection, fp32 epilogue ----------------
__global__ __launch_bounds__(256, 2) void gemm_out(
    const _Float16* __restrict__ A, const _Float16* __restrict__ W,
    const float* __restrict__ bias, float* __restrict__ out) {
  __shared__ __align__(16) _Float16 As[2 * 128 * 32];
  __shared__ __align__(16) _Float16 Bs[2 * 128 * 32];
  const int m0 = blockIdx.x * 128, n0 = blockIdx.y * 128;
  f32x4 acc[4][4] = {};
  gemm128_mainloop(A + (size_t)m0 * 1024, W + (size_t)n0 * 1024, As, Bs, acc);
  const int tid = threadIdx.x;
  const int lane = tid & 63, wid = tid >> 6;
  const int c = lane & 15, quad = lane >> 4;
  const int wm0 = (wid >> 1) * 64, wn0 = (wid & 1) * 64;
#pragma unroll
  for (int j = 0; j < 4; ++j) {
    int n = n0 + wn0 + j * 16 + c;
    float bv = bias[n];
#pragma unroll
    for (int i = 0; i < 4; ++i) {
      int mb = m0 + wm0 + i * 16 + quad * 4;
#pragma unroll
      for (int r = 0; r < 4; ++r) {
        int m = mb + r;
        out[(size_t)m * 1024 + n] = acc[i][j][r] + bv;
      }
    }
  }
}

// ---------------- fused flash attention (buggy-variant-faithful) ----------------
// In-register P transpose via permlane builtins; LDS 32K (Pc buffer deleted).
// REGISTER-BUDGET LESSON (r4/r6): with MFMA in play the allocator splits the
// unified file ~50/50 arch/acc. bound=5 (96 total -> 48 arch) and bound=4
// (128 total -> 64 arch, observed VGPR_Count=64 + 1.7GB scratch writes) both
// spill the ~110-arch-reg live set (s0/s1=64 + oacc + qf + temps).
// bound=3 gives ~170 total -> ~100+ arch: no spill (r3 ran 84 arch at this
// bound). Occupancy is then VGPR-bound at 3-4 blocks/CU; LDS allows 5.
// Keeps: KVBLK=128 (semantics: running-max sequence matches reference BKV
// scan), XCD swizzle, coalesced epilogue, raw exp2.
__global__ __launch_bounds__(256, 3) void fa_kernel(
    const _Float16* __restrict__ Qg, const _Float16* __restrict__ Kg,
    const _Float16* __restrict__ VgT, _Float16* __restrict__ Og) {
  __shared__ __align__(16) _Float16 Ks[128 * 64];    // Q staging, then K (key, d); O staging at epilogue
  __shared__ __align__(16) _Float16 VsT[64 * 128];   // (d, key), swizzled

  const int tid = threadIdx.x;
  const int lane = tid & 63, wid = tid >> 6;
  const int c = lane & 15, quad = lane >> 4;
  // XCD-aware remap: xcd = bid&7 gets swz in [xcd*256, xcd*256+256) =
  // heads [xcd*8, xcd*8+8), all 32 qt each. Bijective (2048 % 8 == 0).
  const int bid = blockIdx.x;
  const int swz = (bid & 7) * 256 + (bid >> 3);
  const int bh = swz >> 5, qt = swz & 31;
  const int b = bh >> 4, h = bh & 15;
  const size_t hoff = (size_t)bh * 4096 * 64;
  const _Float16* Qh = Qg + hoff + (size_t)qt * 128 * 64;
  const _Float16* Kh = Kg + hoff;
  const _Float16* Vh = VgT + hoff;  // (64, 4096)

  // stage Q tile (128x64) into Ks, per-row chunk swizzle
#pragma unroll
  for (int it = 0; it < 4; ++it) {
    int cidx = it * 256 + tid;
    int row = cidx >> 3, ck = (cidx & 7) ^ (row & 7);
    async16(Qh + row * 64 + ck * 8, &Ks[cidx * 8]);
  }
  __syncthreads();

  const int wq0 = wid * 32;
  half8 qf[2][2];
#pragma unroll
  for (int i = 0; i < 2; ++i)
#pragma unroll
    for (int kk = 0; kk < 2; ++kk) {
      int row = wq0 + i * 16 + c;
      int ck = (kk * 4 + quad) ^ (c & 7);
      qf[i][kk] = *(const half8*)&Ks[row * 64 + ck * 8];
    }

  f32x4 oacc[2][4] = {};
  float M[2] = {-__builtin_inff(), -__builtin_inff()};
  float L[2] = {0.f, 0.f};

  for (int j = 0; j < 32; ++j) {
    __syncthreads();  // prior iter's Ks/VsT reads done (and Q-frag reads on j==0)
#pragma unroll
    for (int it = 0; it < 4; ++it) {
      int cidx = it * 256 + tid;
      int row = cidx >> 3, ck = (cidx & 7) ^ (row & 7);
      async16(Kh + (size_t)(j * 128 + row) * 64 + ck * 8, &Ks[cidx * 8]);
    }
#pragma unroll
    for (int it = 0; it < 4; ++it) {
      int cidx = it * 256 + tid;
      int d = cidx >> 4, ck = (cidx & 15) ^ (d & 7);
      async16(Vh + (size_t)d * 4096 + j * 128 + ck * 8, &VsT[cidx * 8]);
    }
    __syncthreads();

    // S^T = K * Q^T for both q-tiles; sacc held in regs until exp phase
    f32x4 s0[8], s1[8];
#pragma unroll
    for (int j8 = 0; j8 < 8; ++j8) {
      int krow = j8 * 16 + c;
      int ck = quad ^ (c & 7);
      half8 kf = *(const half8*)&Ks[krow * 64 + ck * 8];
      f32x4 z = {};
      s0[j8] = __builtin_amdgcn_mfma_f32_16x16x32_f16(kf, qf[0][0], z, 0, 0, 0);
      s1[j8] = __builtin_amdgcn_mfma_f32_16x16x32_f16(kf, qf[1][0], z, 0, 0, 0);
    }
#pragma unroll
    for (int j8 = 0; j8 < 8; ++j8) {
      int krow = j8 * 16 + c;
      int ck = (4 + quad) ^ (c & 7);
      half8 kf = *(const half8*)&Ks[krow * 64 + ck * 8];
      s0[j8] = __builtin_amdgcn_mfma_f32_16x16x32_f16(kf, qf[0][1], s0[j8], 0, 0, 0);
      s1[j8] = __builtin_amdgcn_mfma_f32_16x16x32_f16(kf, qf[1][1], s1[j8], 0, 0, 0);
    }

    // running max per q-tile (max3 tree + cross-quad)
    float Mn[2], al[2];
#pragma unroll
    for (int i = 0; i < 2; ++i) {
      f32x4* s = i ? s1 : s0;
      f32x4 t0 = vmax4_3(s[0], s[1], s[2]);
      f32x4 t1 = vmax4_3(s[3], s[4], s[5]);
      f32x4 t2 = vmax4_3(t0, t1, vmax4(s[6], s[7]));
      float mx = fmaxf(fmaxf(fmaxf(t2[0], t2[1]), t2[2]), t2[3]);
      mx = fmaxf(mx, __shfl_xor(mx, 16));
      mx = fmaxf(mx, __shfl_xor(mx, 32));
      Mn[i] = fmaxf(M[i], mx);
      al[i] = fexp2(M[i] - Mn[i]);
      M[i] = Mn[i];
    }

    // exp + pack + in-register transpose (permlane) + PV, 32 keys per chunk
    f32x4 rs4[2] = {};
#pragma unroll
    for (int ks = 0; ks < 4; ++ks) {
      half8 pf[2];
#pragma unroll
      for (int i = 0; i < 2; ++i) {
        f32x4* s = i ? s1 : s0;
        float mn = Mn[i];
        f32x4 a0 = s[2 * ks] - mn;
        f32x4 a1 = s[2 * ks + 1] - mn;
        f32x4 p0, p1;
        p0[0] = fexp2(a0[0]); p0[1] = fexp2(a0[1]);
        p0[2] = fexp2(a0[2]); p0[3] = fexp2(a0[3]);
        p1[0] = fexp2(a1[0]); p1[1] = fexp2(a1[1]);
        p1[2] = fexp2(a1[2]); p1[3] = fexp2(a1[3]);
        rs4[i] += p0;
        rs4[i] += p1;
        unsigned w0 = __builtin_bit_cast(unsigned, pk_cvt(p0[0], p0[1]));
        unsigned w1 = __builtin_bit_cast(unsigned, pk_cvt(p0[2], p0[3]));
        unsigned w2 = __builtin_bit_cast(unsigned, pk_cvt(p1[0], p1[1]));
        unsigned w3 = __builtin_bit_cast(unsigned, pk_cvt(p1[2], p1[3]));
        plswap32(w0, w2);
        plswap32(w1, w3);
        plswap16(w0, w2);
        plswap16(w1, w3);
        uint4_t uw = {w0, w1, w2, w3};
        pf[i] = __builtin_bit_cast(half8, uw);
      }
#pragma unroll
      for (int n = 0; n < 4; ++n) {
        int d = n * 16 + c;
        int ck = (ks * 4 + quad) ^ (d & 7);
        half8 vf = *(const half8*)&VsT[d * 128 + ck * 8];
        oacc[0][n] = __builtin_amdgcn_mfma_f32_16x16x32_f16(pf[0], vf, oacc[0][n], 0, 0, 0);
        oacc[1][n] = __builtin_amdgcn_mfma_f32_16x16x32_f16(pf[1], vf, oacc[1][n], 0, 0, 0);
      }
    }

#pragma unroll
    for (int i = 0; i < 2; ++i) {
      float rs = (rs4[i][0] + rs4[i][1]) + (rs4[i][2] + rs4[i][3]);
      rs += __shfl_xor(rs, 16);
      rs += __shfl_xor(rs, 32);
      L[i] = al[i] * L[i] + rs;  // L IS rescaled; O is NOT (faithful to reference)
    }
  }

  // ---- epilogue: O/L, staged through Ks for coalesced 128B-row stores ----
  __syncthreads();  // all waves done reading Ks/VsT before Ks is reused
#pragma unroll
  for (int i = 0; i < 2; ++i) {
#pragma unroll
    for (int r = 0; r < 4; ++r) {
      float Lq = __shfl(L[i], quad * 4 + r);
      float inv = 1.0f / Lq;
      int row = wq0 + i * 16 + quad * 4 + r;
#pragma unroll
      for (int n = 0; n < 4; ++n)
        Ks[row * 64 + n * 16 + c] = (_Float16)(oacc[i][n][r] * inv);
    }
  }
  __syncthreads();
  {
    int row = tid >> 1, hf = tid & 1;
    int t = qt * 128 + row;
    size_t base = (((size_t)(b * 4096 + t)) << 10) + h * 64 + hf * 32;
    const half8* srcp = (const half8*)&Ks[row * 64 + hf * 32];
    half8* dstp = (half8*)(Og + base);
    dstp[0] = srcp[0];
    dstp[1] = srcp[1];
    dstp[2] = srcp[2];
    dstp[3] = srcp[3];
  }
}

// ---------------- launcher ----------------
extern "C" void kernel_launch(void* const* d_in, const int* in_sizes, int n_in,
                              void* d_out, int out_size, void* d_ws, size_t ws_size,
                              hipStream_t stream) {
  const float* x = (const float*)d_in[0];
  const float* wq = (const float*)d_in[1];
  const float* bq = (const float*)d_in[2];
  const float* wk = (const float*)d_in[3];
  const float* bk = (const float*)d_in[4];
  const float* wv = (const float*)d_in[5];
  const float* bv = (const float*)d_in[6];
  const float* wo = (const float*)d_in[7];
  const float* bo = (const float*)d_in[8];

  char* ws = (char*)d_ws;
  const size_t MB = 1024 * 1024;
  _Float16* xb = (_Float16*)(ws);               // 32MB; dead after gemm_qkv -> reused as Oatt
  _Float16* wq16 = (_Float16*)(ws + 32 * MB);
  _Float16* wk16 = (_Float16*)(ws + 34 * MB);
  _Float16* wv16 = (_Float16*)(ws + 36 * MB);
  _Float16* wo16 = (_Float16*)(ws + 38 * MB);
  _Float16* Qg = (_Float16*)(ws + 40 * MB);     // (B,H,T,64)
  _Float16* Kg = (_Float16*)(ws + 72 * MB);     // (B,H,T,64)
  _Float16* VgT = (_Float16*)(ws + 104 * MB);   // (B,H,64,T) written directly by gemm_qkv
  _Float16* Oatt = xb;                          // (B,T,1024)

  cvt_f32_f16<<<8192, 256, 0, stream>>>(x, xb, 16777216);
  cvt_w4<<<2048, 256, 0, stream>>>(wq, wk, wv, wo, wq16, wk16, wv16, wo16);

  gemm_qkv<<<dim3(128, 8, 3), 256, 0, stream>>>(xb, wq16, wk16, wv16,
                                                bq, bk, bv, Qg, Kg, VgT);
  fa_kernel<<<dim3(2048), 256, 0, stream>>>(Qg, Kg, VgT, Oatt);
  gemm_out<<<dim3(128, 8), 256, 0, stream>>>(Oatt, wo16, bo, (float*)d_out);
}

// Round 8
// 699.291 us; speedup vs baseline: 2.0844x; 1.0380x over previous
//
#include <hip/hip_runtime.h>
#include <cstdint>
#include <cstddef>

typedef _Float16 half8 __attribute__((ext_vector_type(8)));
typedef _Float16 half4_t __attribute__((ext_vector_type(4)));
typedef _Float16 half2_t __attribute__((ext_vector_type(2)));
typedef float f32x4 __attribute__((ext_vector_type(4)));
typedef unsigned int uint4_t __attribute__((ext_vector_type(4)));
typedef unsigned int uint2_t __attribute__((ext_vector_type(2)));

#define LOG2E 1.4426950408889634f

// async global->LDS, 16B per lane. LDS dest must be wave-uniform base + lane*16.
__device__ __forceinline__ void async16(const void* g, void* l) {
  __builtin_amdgcn_global_load_lds((const __attribute__((address_space(1))) void*)g,
                                   (__attribute__((address_space(3))) void*)l,
                                   16, 0, 0);
}

__device__ __forceinline__ f32x4 vmax4(f32x4 a, f32x4 b) {
  f32x4 r;
  r[0] = fmaxf(a[0], b[0]); r[1] = fmaxf(a[1], b[1]);
  r[2] = fmaxf(a[2], b[2]); r[3] = fmaxf(a[3], b[3]);
  return r;
}

// fmaxf(fmaxf(a,b),c) fuses to v_max3_f32
__device__ __forceinline__ f32x4 vmax4_3(f32x4 a, f32x4 b, f32x4 c) {
  f32x4 r;
  r[0] = fmaxf(fmaxf(a[0], b[0]), c[0]);
  r[1] = fmaxf(fmaxf(a[1], b[1]), c[1]);
  r[2] = fmaxf(fmaxf(a[2], b[2]), c[2]);
  r[3] = fmaxf(fmaxf(a[3], b[3]), c[3]);
  return r;
}

__device__ __forceinline__ half2_t pk_cvt(float a, float b) {
  return __builtin_bit_cast(half2_t, __builtin_amdgcn_cvt_pkrtz(a, b));
}

// raw v_exp_f32 (skips OCML denormal fixup; args are <= 0, outputs in [0,1])
__device__ __forceinline__ float fexp2(float x) { return __builtin_amdgcn_exp2f(x); }

// gfx950 cross-lane swaps via BUILTINS (not inline asm!).
// r5 lesson: raw asm permlane is schedule-dependent-broken (VALU->permlane
// hazard invisible through an asm blob); builtins emit real MIs so the
// backend inserts required wait states under any schedule.
__device__ __forceinline__ void plswap32(unsigned& a, unsigned& b) {
  uint2_t r = __builtin_amdgcn_permlane32_swap(a, b, false, false);
  a = r[0]; b = r[1];
}
__device__ __forceinline__ void plswap16(unsigned& a, unsigned& b) {
  uint2_t r = __builtin_amdgcn_permlane16_swap(a, b, false, false);
  a = r[0]; b = r[1];
}

// ---------------- fp32 -> fp16 convert ----------------
__global__ __launch_bounds__(256) void cvt_f32_f16(const float* __restrict__ in,
                                                   _Float16* __restrict__ out, int n) {
  int i = (blockIdx.x * 256 + threadIdx.x) * 8;
  if (i + 7 < n) {
    f32x4 a = *(const f32x4*)(in + i);
    f32x4 b = *(const f32x4*)(in + i + 4);
    half8 h;
    h[0] = (_Float16)a[0]; h[1] = (_Float16)a[1];
    h[2] = (_Float16)a[2]; h[3] = (_Float16)a[3];
    h[4] = (_Float16)b[0]; h[5] = (_Float16)b[1];
    h[6] = (_Float16)b[2]; h[7] = (_Float16)b[3];
    *(half8*)(out + i) = h;
  }
}

// 4 weight matrices (1M elems each) in one launch
__global__ __launch_bounds__(256) void cvt_w4(
    const float* __restrict__ a, const float* __restrict__ b,
    const float* __restrict__ c, const float* __restrict__ d,
    _Float16* __restrict__ oa, _Float16* __restrict__ ob,
    _Float16* __restrict__ oc, _Float16* __restrict__ od) {
  int seg = blockIdx.x >> 9;
  const float* src = (seg == 0) ? a : (seg == 1) ? b : (seg == 2) ? c : d;
  _Float16* dst = (seg == 0) ? oa : (seg == 1) ? ob : (seg == 2) ? oc : od;
  int i = ((blockIdx.x & 511) * 256 + threadIdx.x) * 8;
  f32x4 x0 = *(const f32x4*)(src + i);
  f32x4 x1 = *(const f32x4*)(src + i + 4);
  half8 h;
  h[0] = (_Float16)x0[0]; h[1] = (_Float16)x0[1];
  h[2] = (_Float16)x0[2]; h[3] = (_Float16)x0[3];
  h[4] = (_Float16)x1[0]; h[5] = (_Float16)x1[1];
  h[6] = (_Float16)x1[2]; h[7] = (_Float16)x1[3];
  *(half8*)(dst + i) = h;
}

// ---------------- shared 128x128x1024 NT-GEMM mainloop ----------------
// Double-buffered LDS, issue-early / sync-late (T3-minimum pipeline).
__device__ __forceinline__ void gemm128_mainloop(const _Float16* __restrict__ Ap,
                                                 const _Float16* __restrict__ Wp,
                                                 _Float16* As, _Float16* Bs,
                                                 f32x4 (&acc)[4][4]) {
  const int tid = threadIdx.x;
  const int lane = tid & 63;
  const int wid = tid >> 6;
  const int c = lane & 15, quad = lane >> 4;
  const int wm0 = (wid >> 1) * 64, wn0 = (wid & 1) * 64;
  const _Float16* ga0 = Ap + (size_t)(tid >> 2) * 1024 + (tid & 3) * 8;
  const _Float16* ga1 = ga0 + (size_t)64 * 1024;
  const _Float16* gb0 = Wp + (size_t)(tid >> 2) * 1024 + (tid & 3) * 8;
  const _Float16* gb1 = gb0 + (size_t)64 * 1024;
  // prologue: stage k0=0 into buffer 0
  async16(ga0, &As[tid * 8]);
  async16(ga1, &As[(tid + 256) * 8]);
  async16(gb0, &Bs[tid * 8]);
  async16(gb1, &Bs[(tid + 256) * 8]);
  __syncthreads();
  for (int k0 = 0; k0 < 1024; k0 += 32) {
    const int curo = ((k0 >> 5) & 1) * (128 * 32);
    if (k0 + 32 < 1024) {
      const int nxto = (128 * 32) - curo;
      async16(ga0 + k0 + 32, &As[nxto + tid * 8]);
      async16(ga1 + k0 + 32, &As[nxto + (tid + 256) * 8]);
      async16(gb0 + k0 + 32, &Bs[nxto + tid * 8]);
      async16(gb1 + k0 + 32, &Bs[nxto + (tid + 256) * 8]);
    }
    half8 af[4], bf[4];
#pragma unroll
    for (int i = 0; i < 4; ++i)
      af[i] = *(const half8*)&As[curo + (wm0 + i * 16 + c) * 32 + quad * 8];
#pragma unroll
    for (int j = 0; j < 4; ++j)
      bf[j] = *(const half8*)&Bs[curo + (wn0 + j * 16 + c) * 32 + quad * 8];
#pragma unroll
    for (int i = 0; i < 4; ++i)
#pragma unroll
      for (int j = 0; j < 4; ++j)
        acc[i][j] = __builtin_amdgcn_mfma_f32_16x16x32_f16(af[i], bf[j], acc[i][j], 0, 0, 0);
    __syncthreads();  // drains next-tile loads (issued a full compute phase ago)
  }
}

// ---------------- QKV projection ----------------
// z=0/1: scatter to (B,H,T,64); z=2: V stored directly TRANSPOSED (B,H,64,T).
__global__ __launch_bounds__(256, 2) void gemm_qkv(
    const _Float16* __restrict__ A,
    const _Float16* __restrict__ Wq, const _Float16* __restrict__ Wk,
    const _Float16* __restrict__ Wv,
    const float* __restrict__ Bq, const float* __restrict__ Bk,
    const float* __restrict__ Bv,
    _Float16* __restrict__ Qo, _Float16* __restrict__ Ko, _Float16* __restrict__ VoT) {
  __shared__ __align__(16) _Float16 As[2 * 128 * 32];
  __shared__ __align__(16) _Float16 Bs[2 * 128 * 32];
  const int z = blockIdx.z;
  const _Float16* W = (z == 0) ? Wq : (z == 1) ? Wk : Wv;
  const float* bias = (z == 0) ? Bq : (z == 1) ? Bk : Bv;
  const float scale = (z == 0) ? LOG2E : 1.0f;  // fold exp->exp2 into Q
  const int m0 = blockIdx.x * 128, n0 = blockIdx.y * 128;
  f32x4 acc[4][4] = {};
  gemm128_mainloop(A + (size_t)m0 * 1024, W + (size_t)n0 * 1024, As, Bs, acc);
  const int tid = threadIdx.x;
  const int lane = tid & 63, wid = tid >> 6;
  const int c = lane & 15, quad = lane >> 4;
  const int wm0 = (wid >> 1) * 64, wn0 = (wid & 1) * 64;
  if (z == 2) {
#pragma unroll
    for (int j = 0; j < 4; ++j) {
      int n = n0 + wn0 + j * 16 + c;
      float bvv = bias[n];
      int h = n >> 6, d = n & 63;
#pragma unroll
      for (int i = 0; i < 4; ++i) {
        int mb = m0 + wm0 + i * 16 + quad * 4;
        int bb = mb >> 12, t = mb & 4095;
        half4_t hv;
#pragma unroll
        for (int r = 0; r < 4; ++r) hv[r] = (_Float16)(acc[i][j][r] + bvv);
        *(half4_t*)&VoT[(((size_t)((bb * 16 + h) * 64 + d)) << 12) + t] = hv;
      }
    }
  } else {
    _Float16* out = (z == 0) ? Qo : Ko;
#pragma unroll
    for (int j = 0; j < 4; ++j) {
      int n = n0 + wn0 + j * 16 + c;
      float bvv = bias[n];
      int h = n >> 6, d = n & 63;
#pragma unroll
      for (int i = 0; i < 4; ++i) {
        int mb = m0 + wm0 + i * 16 + quad * 4;
#pragma unroll
        for (int r = 0; r < 4; ++r) {
          int m = mb + r;
          float v = (acc[i][j][r] + bvv) * scale;
          int bb = m >> 12, t = m & 4095;
          out[(((size_t)(bb * 16 + h) * 4096 + t) << 6) + d] = (_Float16)v;
        }
      }
    }
  }
}

// ---------------- out projection, fp32 epilogue ----------------
__global__ __launch_bounds__(256, 2) void gemm_out(
    const _Float16* __restrict__ A, const _Float16* __restrict__ W,
    const float* __restrict__ bias, float* __restrict__ out) {
  __shared__ __align__(16) _Float16 As[2 * 128 * 32];
  __shared__ __align__(16) _Float16 Bs[2 * 128 * 32];
  const int m0 = blockIdx.x * 128, n0 = blockIdx.y * 128;
  f32x4 acc[4][4] = {};
  gemm128_mainloop(A + (size_t)m0 * 1024, W + (size_t)n0 * 1024, As, Bs, acc);
  const int tid = threadIdx.x;
  const int lane = tid & 63, wid = tid >> 6;
  const int c = lane & 15, quad = lane >> 4;
  const int wm0 = (wid >> 1) * 64, wn0 = (wid & 1) * 64;
#pragma unroll
  for (int j = 0; j < 4; ++j) {
    int n = n0 + wn0 + j * 16 + c;
    float bv = bias[n];
#pragma unroll
    for (int i = 0; i < 4; ++i) {
      int mb = m0 + wm0 + i * 16 + quad * 4;
#pragma unroll
      for (int r = 0; r < 4; ++r) {
        int m = mb + r;
        out[(size_t)m * 1024 + n] = acc[i][j][r] + bv;
      }
    }
  }
}

// ---------------- fused flash attention (buggy-variant-faithful) ----------------
// Round-8: 8 waves x 16 q-rows (512-thread blocks). r7 showed occupancy is
// REGISTER-bound (84 arch + ~80 acc = ~165 unified -> 3 waves/SIMD) even
// though LDS 32K allows 5 blocks. Halving per-wave state (s[8]=32 regs vs 64,
// oacc[4]=16 vs 32, qf[2]=8 vs 16 -> ~95-100 unified) fits 4 waves/SIMD
// under launch_bounds(512,4): 2 blocks/CU x 8 waves = 16 waves/CU = 50%
// ceiling (vs 31%), LDS 2x32K=64K fits. More waves/SIMD covers the per-iter
// barrier+vmcnt drain that 3 lockstep waves couldn't.
// Keeps: KVBLK=128 (semantics: running-max sequence matches reference BKV
// scan), permlane-builtin P transpose, XCD swizzle, coalesced epilogue, exp2.
__global__ __launch_bounds__(512, 4) void fa_kernel(
    const _Float16* __restrict__ Qg, const _Float16* __restrict__ Kg,
    const _Float16* __restrict__ VgT, _Float16* __restrict__ Og) {
  __shared__ __align__(16) _Float16 Ks[128 * 64];    // Q staging, then K (key, d); O staging at epilogue
  __shared__ __align__(16) _Float16 VsT[64 * 128];   // (d, key), swizzled

  const int tid = threadIdx.x;
  const int lane = tid & 63, wid = tid >> 6;   // wid 0..7
  const int c = lane & 15, quad = lane >> 4;
  // XCD-aware remap: xcd = bid&7 gets swz in [xcd*256, xcd*256+256) =
  // heads [xcd*8, xcd*8+8), all 32 qt each. Bijective (2048 % 8 == 0).
  const int bid = blockIdx.x;
  const int swz = (bid & 7) * 256 + (bid >> 3);
  const int bh = swz >> 5, qt = swz & 31;
  const int b = bh >> 4, h = bh & 15;
  const size_t hoff = (size_t)bh * 4096 * 64;
  const _Float16* Qh = Qg + hoff + (size_t)qt * 128 * 64;
  const _Float16* Kh = Kg + hoff;
  const _Float16* Vh = VgT + hoff;  // (64, 4096)

  // stage Q tile (128x64) into Ks, per-row chunk swizzle (512 threads -> 2 its)
#pragma unroll
  for (int it = 0; it < 2; ++it) {
    int cidx = it * 512 + tid;
    int row = cidx >> 3, ck = (cidx & 7) ^ (row & 7);
    async16(Qh + row * 64 + ck * 8, &Ks[cidx * 8]);
  }
  __syncthreads();

  const int wq0 = wid * 16;  // this wave's 16 q-rows
  half8 qf[2];
#pragma unroll
  for (int kk = 0; kk < 2; ++kk) {
    int row = wq0 + c;
    int ck = (kk * 4 + quad) ^ (c & 7);
    qf[kk] = *(const half8*)&Ks[row * 64 + ck * 8];
  }

  f32x4 oacc[4] = {};
  float M = -__builtin_inff();
  float L = 0.f;

  for (int j = 0; j < 32; ++j) {
    __syncthreads();  // prior iter's Ks/VsT reads done (and Q-frag reads on j==0)
#pragma unroll
    for (int it = 0; it < 2; ++it) {
      int cidx = it * 512 + tid;
      int row = cidx >> 3, ck = (cidx & 7) ^ (row & 7);
      async16(Kh + (size_t)(j * 128 + row) * 64 + ck * 8, &Ks[cidx * 8]);
    }
#pragma unroll
    for (int it = 0; it < 2; ++it) {
      int cidx = it * 512 + tid;
      int d = cidx >> 4, ck = (cidx & 15) ^ (d & 7);
      async16(Vh + (size_t)d * 4096 + j * 128 + ck * 8, &VsT[cidx * 8]);
    }
    __syncthreads();

    // S^T = K * Q^T (128 keys x 16 q-rows); held in regs until exp phase
    f32x4 s[8];
#pragma unroll
    for (int j8 = 0; j8 < 8; ++j8) {
      int krow = j8 * 16 + c;
      int ck = quad ^ (c & 7);
      half8 kf = *(const half8*)&Ks[krow * 64 + ck * 8];
      f32x4 z = {};
      s[j8] = __builtin_amdgcn_mfma_f32_16x16x32_f16(kf, qf[0], z, 0, 0, 0);
    }
#pragma unroll
    for (int j8 = 0; j8 < 8; ++j8) {
      int krow = j8 * 16 + c;
      int ck = (4 + quad) ^ (c & 7);
      half8 kf = *(const half8*)&Ks[krow * 64 + ck * 8];
      s[j8] = __builtin_amdgcn_mfma_f32_16x16x32_f16(kf, qf[1], s[j8], 0, 0, 0);
    }

    // running max (max3 tree + cross-quad)
    f32x4 t0 = vmax4_3(s[0], s[1], s[2]);
    f32x4 t1 = vmax4_3(s[3], s[4], s[5]);
    f32x4 t2 = vmax4_3(t0, t1, vmax4(s[6], s[7]));
    float mx = fmaxf(fmaxf(fmaxf(t2[0], t2[1]), t2[2]), t2[3]);
    mx = fmaxf(mx, __shfl_xor(mx, 16));
    mx = fmaxf(mx, __shfl_xor(mx, 32));
    float Mn = fmaxf(M, mx);
    float al = fexp2(M - Mn);
    M = Mn;

    // exp + pack + in-register transpose (permlane) + PV, 32 keys per chunk
    f32x4 rs4 = {};
#pragma unroll
    for (int ks = 0; ks < 4; ++ks) {
      f32x4 a0 = s[2 * ks] - Mn;
      f32x4 a1 = s[2 * ks + 1] - Mn;
      f32x4 p0, p1;
      p0[0] = fexp2(a0[0]); p0[1] = fexp2(a0[1]);
      p0[2] = fexp2(a0[2]); p0[3] = fexp2(a0[3]);
      p1[0] = fexp2(a1[0]); p1[1] = fexp2(a1[1]);
      p1[2] = fexp2(a1[2]); p1[3] = fexp2(a1[3]);
      rs4 += p0;
      rs4 += p1;
      unsigned w0 = __builtin_bit_cast(unsigned, pk_cvt(p0[0], p0[1]));
      unsigned w1 = __builtin_bit_cast(unsigned, pk_cvt(p0[2], p0[3]));
      unsigned w2 = __builtin_bit_cast(unsigned, pk_cvt(p1[0], p1[1]));
      unsigned w3 = __builtin_bit_cast(unsigned, pk_cvt(p1[2], p1[3]));
      plswap32(w0, w2);
      plswap32(w1, w3);
      plswap16(w0, w2);
      plswap16(w1, w3);
      uint4_t uw = {w0, w1, w2, w3};
      half8 pf = __builtin_bit_cast(half8, uw);
#pragma unroll
      for (int n = 0; n < 4; ++n) {
        int d = n * 16 + c;
        int ck = (ks * 4 + quad) ^ (d & 7);
        half8 vf = *(const half8*)&VsT[d * 128 + ck * 8];
        oacc[n] = __builtin_amdgcn_mfma_f32_16x16x32_f16(pf, vf, oacc[n], 0, 0, 0);
      }
    }

    float rs = (rs4[0] + rs4[1]) + (rs4[2] + rs4[3]);
    rs += __shfl_xor(rs, 16);
    rs += __shfl_xor(rs, 32);
    L = al * L + rs;  // L IS rescaled; O is NOT (faithful to reference)
  }

  // ---- epilogue: O/L, staged through Ks for coalesced 128B-row stores ----
  __syncthreads();  // all waves done reading Ks/VsT before Ks is reused
#pragma unroll
  for (int r = 0; r < 4; ++r) {
    float Lq = __shfl(L, quad * 4 + r);
    float inv = 1.0f / Lq;
    int row = wq0 + quad * 4 + r;
#pragma unroll
    for (int n = 0; n < 4; ++n)
      Ks[row * 64 + n * 16 + c] = (_Float16)(oacc[n][r] * inv);
  }
  __syncthreads();
  {
    int row = tid >> 2, part = tid & 3;  // 512 threads: 4 threads per 128B row
    int t = qt * 128 + row;
    size_t base = (((size_t)(b * 4096 + t)) << 10) + h * 64 + part * 16;
    const half8* srcp = (const half8*)&Ks[row * 64 + part * 16];
    half8* dstp = (half8*)(Og + base);
    dstp[0] = srcp[0];
    dstp[1] = srcp[1];
  }
}

// ---------------- launcher ----------------
extern "C" void kernel_launch(void* const* d_in, const int* in_sizes, int n_in,
                              void* d_out, int out_size, void* d_ws, size_t ws_size,
                              hipStream_t stream) {
  const float* x = (const float*)d_in[0];
  const float* wq = (const float*)d_in[1];
  const float* bq = (const float*)d_in[2];
  const float* wk = (const float*)d_in[3];
  const float* bk = (const float*)d_in[4];
  const float* wv = (const float*)d_in[5];
  const float* bv = (const float*)d_in[6];
  const float* wo = (const float*)d_in[7];
  const float* bo = (const float*)d_in[8];

  char* ws = (char*)d_ws;
  const size_t MB = 1024 * 1024;
  _Float16* xb = (_Float16*)(ws);               // 32MB; dead after gemm_qkv -> reused as Oatt
  _Float16* wq16 = (_Float16*)(ws + 32 * MB);
  _Float16* wk16 = (_Float16*)(ws + 34 * MB);
  _Float16* wv16 = (_Float16*)(ws + 36 * MB);
  _Float16* wo16 = (_Float16*)(ws + 38 * MB);
  _Float16* Qg = (_Float16*)(ws + 40 * MB);     // (B,H,T,64)
  _Float16* Kg = (_Float16*)(ws + 72 * MB);     // (B,H,T,64)
  _Float16* VgT = (_Float16*)(ws + 104 * MB);   // (B,H,64,T) written directly by gemm_qkv
  _Float16* Oatt = xb;                          // (B,T,1024)

  cvt_f32_f16<<<8192, 256, 0, stream>>>(x, xb, 16777216);
  cvt_w4<<<2048, 256, 0, stream>>>(wq, wk, wv, wo, wq16, wk16, wv16, wo16);

  gemm_qkv<<<dim3(128, 8, 3), 256, 0, stream>>>(xb, wq16, wk16, wv16,
                                                bq, bk, bv, Qg, Kg, VgT);
  fa_kernel<<<dim3(2048), 512, 0, stream>>>(Qg, Kg, VgT, Oatt);
  gemm_out<<<dim3(128, 8), 256, 0, stream>>>(Oatt, wo16, bo, (float*)d_out);
}